// Round 5
// baseline (248.719 us; speedup 1.0000x reference)
//
#include <hip/hip_runtime.h>
#include <hip/hip_bf16.h>

typedef __hip_bfloat16 BF;
typedef __attribute__((ext_vector_type(8))) short bf16x8;
typedef __attribute__((ext_vector_type(4))) float f32x4;
typedef __attribute__((ext_vector_type(4))) unsigned short us4;

// B=2, C=128, H=W=128, K=8, STRIDE=2, DIL=2, NH=8, dh=16, HID=170, Hc=Wc=64
// fp32 in / fp32 out. MFMA (bf16, fp32 acc) everywhere.
// ws (floats): xt[0,4194304) kcb[+1048576) vcb[+1048576) ; packs (bf16) at 6291456

#define ASTR 200   // k_cell Abuf row stride (bf16)
#define KSTR 136   // k_pre(kv) Abuf row stride (bf16)

__device__ __forceinline__ short bfr(float f){
  union{float f; unsigned u;} c; c.f = f;
  const unsigned u = c.u + 0x7FFFu + ((c.u >> 16) & 1u);
  return (short)(u >> 16);
}
__device__ __forceinline__ bf16x8 pk8(float4 a, float4 b){
  bf16x8 r;
  r[0]=bfr(a.x); r[1]=bfr(a.y); r[2]=bfr(a.z); r[3]=bfr(a.w);
  r[4]=bfr(b.x); r[5]=bfr(b.y); r[6]=bfr(b.z); r[7]=bfr(b.w);
  return r;
}

// sum-reduce 16 vals across a 128-thr half (2 waves) of a 256-thr block
__device__ __forceinline__ void gsum16h(float v[16], float* red, int tid){
  #pragma unroll
  for(int s = 1; s < 64; s <<= 1){
    #pragma unroll
    for(int i = 0; i < 16; i++) v[i] += __shfl_xor(v[i], s);
  }
  const int wid = tid >> 6, half = tid >> 7;
  __syncthreads();
  if((tid & 63) == 0){
    #pragma unroll
    for(int i = 0; i < 16; i++) red[wid*16 + i] = v[i];
  }
  __syncthreads();
  #pragma unroll
  for(int i = 0; i < 16; i++) v[i] = red[half*32 + i] + red[half*32 + 16 + i];
}

// per-half row-stat reduction (k_pre kv)
__device__ __forceinline__ void rowredh(float s1[4], float s2[4], float* red, int tid){
  const int lane = tid & 63, wid = tid >> 6, half = tid >> 7;
  #pragma unroll
  for(int m = 1; m < 16; m <<= 1){
    #pragma unroll
    for(int r = 0; r < 4; r++){ s1[r] += __shfl_xor(s1[r], m); s2[r] += __shfl_xor(s2[r], m); }
  }
  const int q4 = lane >> 4;
  __syncthreads();
  if((lane & 15) == 0){
    #pragma unroll
    for(int r = 0; r < 4; r++){
      red[wid*32 + q4*4 + r]      = s1[r];
      red[wid*32 + 16 + q4*4 + r] = s2[r];
    }
  }
  __syncthreads();
  #pragma unroll
  for(int r = 0; r < 4; r++){
    s1[r] = red[half*64 + q4*4 + r]      + red[half*64 + 32 + q4*4 + r];
    s2[r] = red[half*64 + 16 + q4*4 + r] + red[half*64 + 48 + q4*4 + r];
  }
}

// 4-wave row-stat reduction (k_cell): rows 0..15 = px, stats over 128 cols
__device__ __forceinline__ void rowred4(float s1[4], float s2[4], float* red,
                                        int wave, int lane){
  #pragma unroll
  for(int m = 1; m < 16; m <<= 1){
    #pragma unroll
    for(int r = 0; r < 4; r++){ s1[r] += __shfl_xor(s1[r], m); s2[r] += __shfl_xor(s2[r], m); }
  }
  const int q4 = lane >> 4;
  __syncthreads();
  if((lane & 15) == 0){
    #pragma unroll
    for(int r = 0; r < 4; r++){
      red[wave*32 + q4*4 + r]      = s1[r];
      red[wave*32 + 16 + q4*4 + r] = s2[r];
    }
  }
  __syncthreads();
  #pragma unroll
  for(int r = 0; r < 4; r++){
    s1[r] = red[q4*4 + r] + red[32 + q4*4 + r] + red[64 + q4*4 + r] + red[96 + q4*4 + r];
    s2[r] = red[16 + q4*4 + r] + red[48 + q4*4 + r] + red[80 + q4*4 + r] + red[112 + q4*4 + r];
  }
}

// ---- K_pre: fused {transpose x->xt | weight pack | coarse k,v} ----
// kv reads x AND qkv_w directly (no dependency on the pack section -> no race).
__global__ void __launch_bounds__(256)
k_pre(const float* __restrict__ x,
      const float* __restrict__ qkv_w, const float* __restrict__ proj_w,
      const float* __restrict__ fc1_w, const float* __restrict__ fc2_w,
      const float* __restrict__ qkv_b,
      const float* __restrict__ kg, const float* __restrict__ kb,
      const float* __restrict__ n1g, const float* __restrict__ n1b,
      float* __restrict__ xt, BF* __restrict__ pk,
      float* __restrict__ kcb, float* __restrict__ vcb){
  __shared__ __align__(16) unsigned char sm[16640];
  const int bx = blockIdx.x, tid = threadIdx.x;

  if(bx < 1024){                       // ---- transpose x (B,C,H,W) -> xt (B,HW,C)
    float (*tile)[65] = (float(*)[65])sm;
    const int b = bx >> 9, r2 = bx & 511;
    const int pb = (r2 & 255) * 64, cb = (r2 >> 8) * 64;
    const int tx = tid & 63, ty = tid >> 6;
    #pragma unroll
    for(int r = 0; r < 64; r += 4)
      tile[ty+r][tx] = x[(size_t)(b*128 + cb+ty+r)*16384 + pb + tx];
    __syncthreads();
    #pragma unroll
    for(int r = 0; r < 64; r += 4)
      xt[(size_t)((b<<14) + pb + ty + r)*128 + cb + tx] = tile[tx][ty+r];
    return;
  }
  if(bx < 1464){                       // ---- weight pack (consumed by k_cell only)
    const int idx = (bx - 1024) * 256 + tid;
    if(idx >= 112640) return;
    float val;
    if(idx < 49152){
      const int reg = idx >> 14, l = idx & 16383;
      const int j = l & 7, q = (l>>3)&3, n = (l>>5)&127, s = l>>12;
      val = qkv_w[(reg*128 + n)*128 + (s*32 + q*8 + j)];
    } else if(idx < 65536){
      const int l = idx - 49152;
      const int j = l&7, q=(l>>3)&3, n=(l>>5)&127, s=l>>12;
      val = proj_w[n*128 + (s*32+q*8+j)];
    } else if(idx < 88064){
      const int l = idx - 65536;
      const int j = l&7, q=(l>>3)&3, rem = l>>5;
      const int n = rem % 176, s = rem / 176;
      const int k = s*32+q*8+j;
      val = (n < 170) ? fc1_w[n*128 + k] : 0.f;
    } else {
      const int l = idx - 88064;
      const int j = l&7, q=(l>>3)&3, n=(l>>5)&127, s=l>>12;
      const int k = s*32+q*8+j;
      val = (k < 170) ? fc2_w[n*170 + k] : 0.f;
    }
    pk[idx] = __float2bfloat16(val);
    return;
  }

  // ---- kv: 16 coarse px/block, two independent 128-thr halves ----
  BF* const Abuf = (BF*)sm;                    // 2 halves x [16][KSTR]
  float* const red = (float*)(sm + 8704);      // 128 floats
  const int bx2 = bx - 1464;
  const int lane = tid & 63, half = tid >> 7, wh = (tid >> 6) & 1, c = tid & 127;
  const int l15 = lane & 15, q4 = lane >> 4;
  const int cp0 = bx2 * 16;
  const int b = cp0 >> 12, ic = (cp0 & 4095) >> 6, jb = cp0 & 63;
  BF* const AbufH = Abuf + half*16*KSTR;

  float xv[8];
  {
    const size_t off = (size_t)(b*128 + c)*16384 + (size_t)(2*ic)*128 + 2*(jb + half*8);
    const float4* xp4 = (const float4*)(x + off);
    const float4 f0 = xp4[0], f1 = xp4[1], f2 = xp4[2], f3 = xp4[3];
    xv[0]=f0.x; xv[1]=f0.z; xv[2]=f1.x; xv[3]=f1.z;
    xv[4]=f2.x; xv[5]=f2.z; xv[6]=f3.x; xv[7]=f3.z;
  }
  float st[16];
  #pragma unroll
  for(int r = 0; r < 8; r++){ st[r] = xv[r]; st[8+r] = xv[r]*xv[r]; }
  gsum16h(st, red, tid);
  {
    const float g = n1g[c], be = n1b[c];
    #pragma unroll
    for(int r = 0; r < 8; r++){
      const float mu = st[r]*(1.f/128.f);
      const float var = st[8+r]*(1.f/128.f) - mu*mu;
      AbufH[r*KSTR + c] = __float2bfloat16((xv[r]-mu)*rsqrtf(var+1e-6f)*g + be);
    }
  }
  __syncthreads();
  bf16x8 af[4];
  #pragma unroll
  for(int s = 0; s < 4; s++) af[s] = *(const bf16x8*)&AbufH[l15*KSTR + s*32 + q4*8];

  // ---- k GEMM (B-fragments straight from qkv_w, bf16-packed inline) ----
  f32x4 acc[4];
  #pragma unroll
  for(int nt = 0; nt < 4; nt++){ acc[nt][0]=0.f; acc[nt][1]=0.f; acc[nt][2]=0.f; acc[nt][3]=0.f; }
  #pragma unroll
  for(int nt = 0; nt < 4; nt++){
    const int n = (wh*4+nt)*16 + l15;
    #pragma unroll
    for(int s = 0; s < 4; s++){
      const float* wp = qkv_w + (size_t)(128 + n)*128 + s*32 + q4*8;
      acc[nt] = __builtin_amdgcn_mfma_f32_16x16x32_bf16(
        af[s], pk8(*(const float4*)wp, *(const float4*)(wp+4)), acc[nt], 0,0,0);
    }
  }
  float s1[4], s2[4];
  #pragma unroll
  for(int r = 0; r < 4; r++){ s1[r]=0.f; s2[r]=0.f; }
  #pragma unroll
  for(int nt = 0; nt < 4; nt++){
    const float colb = qkv_b[128 + (wh*4+nt)*16 + l15];
    #pragma unroll
    for(int r = 0; r < 4; r++){
      const float vv = acc[nt][r] + colb;
      acc[nt][r] = vv; s1[r] += vv; s2[r] += vv*vv;
    }
  }
  rowredh(s1, s2, red, tid);
  #pragma unroll
  for(int nt = 0; nt < 4; nt++){
    const int col = (wh*4+nt)*16 + l15;
    const float g = kg[col], be = kb[col];
    #pragma unroll
    for(int r = 0; r < 4; r++){
      const int row = q4*4 + r;
      if(row < 8){
        const float mu = s1[r]*(1.f/128.f);
        const float var = s2[r]*(1.f/128.f) - mu*mu;
        kcb[(size_t)(cp0 + half*8 + row)*128 + col] = (acc[nt][r]-mu)*rsqrtf(var+1e-6f)*g + be;
      }
    }
  }
  // ---- v GEMM ----
  #pragma unroll
  for(int nt = 0; nt < 4; nt++){ acc[nt][0]=0.f; acc[nt][1]=0.f; acc[nt][2]=0.f; acc[nt][3]=0.f; }
  #pragma unroll
  for(int nt = 0; nt < 4; nt++){
    const int n = (wh*4+nt)*16 + l15;
    #pragma unroll
    for(int s = 0; s < 4; s++){
      const float* wp = qkv_w + (size_t)(256 + n)*128 + s*32 + q4*8;
      acc[nt] = __builtin_amdgcn_mfma_f32_16x16x32_bf16(
        af[s], pk8(*(const float4*)wp, *(const float4*)(wp+4)), acc[nt], 0,0,0);
    }
  }
  #pragma unroll
  for(int nt = 0; nt < 4; nt++){
    const int col = (wh*4+nt)*16 + l15;
    const float bv = qkv_b[256 + col];
    #pragma unroll
    for(int r = 0; r < 4; r++){
      const int row = q4*4 + r;
      if(row < 8) vcb[(size_t)(cp0 + half*8 + row)*128 + col] = acc[nt][r] + bv;
    }
  }
}

// ---- K_cell: 256 thr / 16 px (4 cells, 4x4 spatial tile) / all-MFMA ----
// px p: h = 4ip + (p>>2), w = 4jq + (p&3); cell(p) = 2*(p>>3) + ((p>>1)&1);
// lp(p) = 2*((p>>2)&1) + (p&1). Wave w owns cell w for attention.
// LDS 31488B -> 5 blocks/CU (20 waves): uni 18432 (Abuf[16][200] U 4 waves x
// {Vt[16][72], Pb[16][72]}) + xvL 8192 + qnH 4352 (red aliased) + cidx 512.
__global__ void __launch_bounds__(256, 5)
k_cell(const float* __restrict__ xt_in,
       const BF* __restrict__ packQ, const BF* __restrict__ packP,
       const BF* __restrict__ packF1, const BF* __restrict__ packF2,
       const float* __restrict__ qkv_b,
       const float* __restrict__ qg, const float* __restrict__ qb,
       const float* __restrict__ n1g, const float* __restrict__ n1b,
       const float* __restrict__ proj_b,
       const float* __restrict__ ls1, const float* __restrict__ ls2,
       const float* __restrict__ n2g, const float* __restrict__ n2b,
       const float* __restrict__ fc1_b,
       const float* __restrict__ mg, const float* __restrict__ mb,
       const float* __restrict__ fc2_b,
       const float* __restrict__ kcb, const float* __restrict__ vcb,
       float* __restrict__ xt_out){
  __shared__ __align__(16) BF uni[9216];
  BF* const Abuf = uni;                        // [16][ASTR]
  __shared__ float xvL[2048];                  // [16px][128ch]
  __shared__ __align__(16) ushort qnH[2176];   // [4cell][136pad][4lp]
  __shared__ ushort cidx2[256];                // [4cell][64] safe coarse idx
  float* const red = (float*)qnH;              // 128 floats, disjoint live range
  const int tid = threadIdx.x, wave = tid>>6, lane = tid&63;
  const int l15 = lane & 15, q4 = lane >> 4;

  // XCD-aware swizzle (bijective: 2048 % 8 == 0, chunks of 256 per XCD)
  const int bx0 = blockIdx.x;
  const int bx = ((bx0 & 7) << 8) | (bx0 >> 3);
  const int b = bx >> 10, rem = bx & 1023, ip = rem >> 5, jq = rem & 31;
  const size_t p0 = (size_t)b*2097152 + (size_t)(512*ip + 4*jq)*128;
  const int c = tid & 127, half = tid >> 7;

  float xv[8];
  #pragma unroll
  for(int r = 0; r < 8; r++){
    const int p = half*8 + r;
    const size_t pr = p0 + ((size_t)(p>>2)<<14) + (size_t)((p&3)<<7);
    xv[r] = xt_in[pr + c];
    xvL[p*128 + c] = xv[r];
  }
  {                                            // neighbor indices, 4 cells
    const int cell = tid >> 6, e = tid & 63;
    const int i = e >> 3, j = e & 7;
    const int ic = 2*ip + (cell>>1), jcc = 2*jq + (cell&1);
    const int ri = ic + 2*i - 8, rj = jcc + 2*j - 8;
    const bool ok = (rj >= 0) && (rj < 64) && (ri >= 0) && (ri < 64);
    cidx2[cell*64 + e] = ok ? (ushort)(b*4096 + ri*64 + rj) : (ushort)0;
  }

  // ---- LN1 ----
  float st[16];
  #pragma unroll
  for(int r = 0; r < 8; r++){ st[r] = xv[r]; st[8+r] = xv[r]*xv[r]; }
  gsum16h(st, red, tid);
  {
    const float g = n1g[c], be = n1b[c];
    #pragma unroll
    for(int r = 0; r < 8; r++){
      const int p = half*8 + r;
      const float mu = st[r]*(1.f/128.f);
      const float var = st[8+r]*(1.f/128.f) - mu*mu;
      Abuf[p*ASTR + c] = __float2bfloat16((xv[r]-mu)*rsqrtf(var+1e-6f)*g + be);
    }
  }
  __syncthreads();

  // ---- q GEMM (M=16) + q-LN -> qnH ----
  {
    bf16x8 af[4];
    #pragma unroll
    for(int s = 0; s < 4; s++) af[s] = *(const bf16x8*)&Abuf[l15*ASTR + s*32 + q4*8];
    f32x4 acc[2];
    #pragma unroll
    for(int nt = 0; nt < 2; nt++){ acc[nt][0]=0.f; acc[nt][1]=0.f; acc[nt][2]=0.f; acc[nt][3]=0.f; }
    #pragma unroll
    for(int nt = 0; nt < 2; nt++){
      const int n = (wave*2+nt)*16 + l15;
      #pragma unroll
      for(int s = 0; s < 4; s++){
        bf16x8 bf = *(const bf16x8*)&packQ[((s*128 + n)*4 + q4)*8];
        acc[nt] = __builtin_amdgcn_mfma_f32_16x16x32_bf16(af[s], bf, acc[nt], 0,0,0);
      }
    }
    float s1[4], s2[4];
    #pragma unroll
    for(int r = 0; r < 4; r++){ s1[r]=0.f; s2[r]=0.f; }
    #pragma unroll
    for(int nt = 0; nt < 2; nt++){
      const float cb2 = qkv_b[(wave*2+nt)*16 + l15];
      #pragma unroll
      for(int r = 0; r < 4; r++){
        const float vv = acc[nt][r] + cb2;
        acc[nt][r] = vv; s1[r] += vv; s2[r] += vv*vv;
      }
    }
    rowred4(s1, s2, red, wave, lane);
    short tw[2][4];
    {
      float mu[4], rs[4];
      #pragma unroll
      for(int r = 0; r < 4; r++){
        mu[r] = s1[r]*(1.f/128.f);
        rs[r] = rsqrtf(s2[r]*(1.f/128.f) - mu[r]*mu[r] + 1e-6f);
      }
      #pragma unroll
      for(int nt = 0; nt < 2; nt++){
        const int col = (wave*2+nt)*16 + l15;
        const float g = qg[col], be = qb[col];
        #pragma unroll
        for(int r = 0; r < 4; r++)
          tw[nt][r] = bfr((acc[nt][r]-mu[r])*rs[r]*g + be);
      }
    }
    __syncthreads();            // red (aliased with qnH) fully consumed
    #pragma unroll
    for(int nt = 0; nt < 2; nt++){
      const int col = (wave*2+nt)*16 + l15;
      const int colp = col + (col >> 4);
      #pragma unroll
      for(int r = 0; r < 4; r++){
        const int cell = 2*(q4>>1) + ((r>>1)&1);
        const int lp   = 2*(q4&1) + (r&1);
        qnH[cell*544 + colp*4 + lp] = (ushort)tw[nt][r];
      }
    }
  }
  __syncthreads();

  // ---- attention: wave w owns cell w, 2 head-groups, no inner barriers ----
  const int hsub = l15 >> 2, px = l15 & 3;
  const int par = q4 >> 1, dbase = (q4 & 1) * 8;
  BF* const attw = uni + wave*2304;
  ushort* const Vt = (ushort*)attw;            // [16][72]
  ushort* const Pb = (ushort*)(attw + 1152);   // [16][72]
  const ushort* cidx = cidx2 + wave*64;
  const ushort* qp = qnH + wave*544;
  const int ic = 2*ip + (wave>>1), jcc = 2*jq + (wave&1);
  const int i0 = l15 >> 3;
  const int rj = jcc + 2*(l15 & 7) - 8;
  const bool vj = (rj >= 0) && (rj < 64);
  float madd[4];
  #pragma unroll
  for(int nt = 0; nt < 4; nt++){
    const int ri = ic + 2*(nt*2 + i0) - 8;
    madd[nt] = (vj && ri >= 0 && ri < 64) ? 0.f : -1e30f;
  }

  f32x4 oC[2];
  #pragma unroll
  for(int hg = 0; hg < 2; hg++){
    // block-diagonal q A-fragments
    bf16x8 afq0, afq1;
    {
      const int idx0 = (hg*64 + hsub*16 + dbase + (hg*4 + hsub))*4 + px;
      short bq[8];
      #pragma unroll
      for(int j = 0; j < 8; j++) bq[j] = (short)qp[idx0 + 4*j];
      const bool a0 = (par == hsub), a1 = ((2 + par) == hsub);
      #pragma unroll
      for(int j = 0; j < 8; j++){
        afq0[j] = a0 ? bq[j] : (short)0;
        afq1[j] = a1 ? bq[j] : (short)0;
      }
    }
    // QK: 8 MFMA
    f32x4 accq[4];
    #pragma unroll
    for(int nt = 0; nt < 4; nt++){ accq[nt][0]=0.f; accq[nt][1]=0.f; accq[nt][2]=0.f; accq[nt][3]=0.f; }
    #pragma unroll
    for(int nt = 0; nt < 4; nt++){
      const float* kp = kcb + ((size_t)cidx[nt*16 + l15] << 7) + hg*64 + q4*8;
      const float4 k00 = *(const float4*)kp;
      const float4 k01 = *(const float4*)(kp + 4);
      const float4 k10 = *(const float4*)(kp + 32);
      const float4 k11 = *(const float4*)(kp + 36);
      accq[nt] = __builtin_amdgcn_mfma_f32_16x16x32_bf16(afq0, pk8(k00,k01), accq[nt], 0,0,0);
      accq[nt] = __builtin_amdgcn_mfma_f32_16x16x32_bf16(afq1, pk8(k10,k11), accq[nt], 0,0,0);
    }
    // softmax in-register; unnormalized e (bf16) -> Pb
    float inv[4];
    #pragma unroll
    for(int reg = 0; reg < 4; reg++){
      const float s0 = accq[0][reg]*0.25f + madd[0];
      const float s1 = accq[1][reg]*0.25f + madd[1];
      const float s2 = accq[2][reg]*0.25f + madd[2];
      const float s3 = accq[3][reg]*0.25f + madd[3];
      float m = fmaxf(fmaxf(s0,s1), fmaxf(s2,s3));
      #pragma unroll
      for(int sft = 1; sft < 16; sft <<= 1) m = fmaxf(m, __shfl_xor(m, sft));
      const float e0 = __expf(s0-m), e1 = __expf(s1-m);
      const float e2 = __expf(s2-m), e3 = __expf(s3-m);
      ushort* pr = Pb + (q4*4 + reg)*72 + l15;
      pr[0]  = (ushort)bfr(e0);
      pr[16] = (ushort)bfr(e1);
      pr[32] = (ushort)bfr(e2);
      pr[48] = (ushort)bfr(e3);
      float es = e0+e1+e2+e3;
      #pragma unroll
      for(int sft = 1; sft < 16; sft <<= 1) es += __shfl_xor(es, sft);
      inv[reg] = 1.f/es;
    }
    const bf16x8 pa0 = *(const bf16x8*)(Pb + l15*72 + q4*8);
    const bf16x8 pa1 = *(const bf16x8*)(Pb + l15*72 + 32 + q4*8);

    // PV: per head stage V, 2 MFMA; keep own head's rows
    f32x4 oSel; oSel[0]=0.f; oSel[1]=0.f; oSel[2]=0.f; oSel[3]=0.f;
    #pragma unroll
    for(int hs = 0; hs < 4; hs++){
      const int h = hg*4 + hs;
      float4 vv[4];
      #pragma unroll
      for(int it = 0; it < 4; it++)
        vv[it] = *(const float4*)(vcb + ((size_t)cidx[l15*4 + it] << 7) + h*16 + q4*4);
      #pragma unroll
      for(int dd = 0; dd < 4; dd++){
        us4 w;
        w[0] = (unsigned short)bfr(((const float*)&vv[0])[dd]);
        w[1] = (unsigned short)bfr(((const float*)&vv[1])[dd]);
        w[2] = (unsigned short)bfr(((const float*)&vv[2])[dd]);
        w[3] = (unsigned short)bfr(((const float*)&vv[3])[dd]);
        *(us4*)(Vt + (q4*4 + dd)*72 + l15*4) = w;
      }
      const bf16x8 bv0 = *(const bf16x8*)(Vt + l15*72 + q4*8);
      const bf16x8 bv1 = *(const bf16x8*)(Vt + l15*72 + 32 + q4*8);
      f32x4 accv; accv[0]=0.f; accv[1]=0.f; accv[2]=0.f; accv[3]=0.f;
      accv = __builtin_amdgcn_mfma_f32_16x16x32_bf16(pa0, bv0, accv, 0,0,0);
      accv = __builtin_amdgcn_mfma_f32_16x16x32_bf16(pa1, bv1, accv, 0,0,0);
      if(q4 == hs){ oSel[0]=accv[0]; oSel[1]=accv[1]; oSel[2]=accv[2]; oSel[3]=accv[3]; }
    }
    oC[hg][0] = oSel[0]*inv[0]; oC[hg][1] = oSel[1]*inv[1];
    oC[hg][2] = oSel[2]*inv[2]; oC[hg][3] = oSel[3]*inv[3];
  }
  __syncthreads();
  // ao -> Abuf[px p][head*16 + d]
  {
    ushort* ab = (ushort*)Abuf;
    #pragma unroll
    for(int hg = 0; hg < 2; hg++){
      const int col = (hg*4 + q4)*16 + l15;
      #pragma unroll
      for(int reg = 0; reg < 4; reg++){
        const int row_p = 8*(wave>>1) + 4*(reg>>1) + 2*(wave&1) + (reg&1);
        ab[row_p*ASTR + col] = (ushort)bfr(oC[hg][reg]);
      }
    }
  }
  __syncthreads();

  // ---- proj GEMM + ls1*res -> xh, LN2 -> Abuf ----
  float xh[2][4];
  {
    bf16x8 af[4];
    #pragma unroll
    for(int s = 0; s < 4; s++) af[s] = *(const bf16x8*)&Abuf[l15*ASTR + s*32 + q4*8];
    f32x4 acc[2];
    #pragma unroll
    for(int nt = 0; nt < 2; nt++){ acc[nt][0]=0.f; acc[nt][1]=0.f; acc[nt][2]=0.f; acc[nt][3]=0.f; }
    #pragma unroll
    for(int nt = 0; nt < 2; nt++){
      const int n = (wave*2+nt)*16 + l15;
      #pragma unroll
      for(int s = 0; s < 4; s++){
        bf16x8 bf = *(const bf16x8*)&packP[((s*128 + n)*4 + q4)*8];
        acc[nt] = __builtin_amdgcn_mfma_f32_16x16x32_bf16(af[s], bf, acc[nt], 0,0,0);
      }
    }
    float s1[4], s2[4];
    #pragma unroll
    for(int r = 0; r < 4; r++){ s1[r]=0.f; s2[r]=0.f; }
    #pragma unroll
    for(int nt = 0; nt < 2; nt++){
      const int col = (wave*2+nt)*16 + l15;
      const float bp = proj_b[col], l1 = ls1[col];
      #pragma unroll
      for(int r = 0; r < 4; r++){
        const int p = q4*4 + r;
        const float hx = xvL[p*128 + col] + l1*(acc[nt][r] + bp);
        xh[nt][r] = hx; s1[r] += hx; s2[r] += hx*hx;
      }
    }
    rowred4(s1, s2, red, wave, lane);
    #pragma unroll
    for(int nt = 0; nt < 2; nt++){
      const int col = (wave*2+nt)*16 + l15;
      const float g2 = n2g[col], be = n2b[col];
      #pragma unroll
      for(int r = 0; r < 4; r++){
        const int p = q4*4 + r;
        const float mu = s1[r]*(1.f/128.f);
        const float var = s2[r]*(1.f/128.f) - mu*mu;
        Abuf[p*ASTR + col] =
          __float2bfloat16((xh[nt][r]-mu)*rsqrtf(var+1e-6f)*g2 + be);
      }
    }
  }
  __syncthreads();

  // ---- fc1 GEMM (N=176, tiles 3/3/3/2) + midLN + gelu -> Abuf ----
  {
    bf16x8 af[4];
    #pragma unroll
    for(int s = 0; s < 4; s++) af[s] = *(const bf16x8*)&Abuf[l15*ASTR + s*32 + q4*8];
    const int NT1 = (wave < 3) ? 3 : 2;
    const int tb  = (wave < 3) ? wave*3 : 9;
    f32x4 acc1[3];
    #pragma unroll
    for(int nt = 0; nt < 3; nt++){ acc1[nt][0]=0.f; acc1[nt][1]=0.f; acc1[nt][2]=0.f; acc1[nt][3]=0.f; }
    for(int nt = 0; nt < NT1; nt++){
      const int n = (tb + nt)*16 + l15;
      #pragma unroll
      for(int s = 0; s < 4; s++){
        bf16x8 bf = *(const bf16x8*)&packF1[((s*176 + n)*4 + q4)*8];
        acc1[nt] = __builtin_amdgcn_mfma_f32_16x16x32_bf16(af[s], bf, acc1[nt], 0,0,0);
      }
    }
    float s1[4], s2[4];
    #pragma unroll
    for(int r = 0; r < 4; r++){ s1[r]=0.f; s2[r]=0.f; }
    for(int nt = 0; nt < NT1; nt++){
      const int col = (tb + nt)*16 + l15;
      const float b1 = (col < 170) ? fc1_b[col] : 0.f;
      #pragma unroll
      for(int r = 0; r < 4; r++){
        const float vv = acc1[nt][r] + b1;
        acc1[nt][r] = vv; s1[r] += vv; s2[r] += vv*vv;
      }
    }
    rowred4(s1, s2, red, wave, lane);
    for(int z = tid; z < 352; z += 256){          // zero fc2 K-pad cols 170..191
      const int row = z / 22, colz = 170 + (z - (z/22)*22);
      Abuf[row*ASTR + colz] = __float2bfloat16(0.f);
    }
    const float kA = 0.7978845608028654f, kB = 0.044715f;
    for(int nt = 0; nt < NT1; nt++){
      const int col = (tb + nt)*16 + l15;
      if(col < 170){
        const float g2 = mg[col], be = mb[col];
        #pragma unroll
        for(int r = 0; r < 4; r++){
          const int p = q4*4 + r;
          const float mu = s1[r]*(1.f/170.f);
          const float var = s2[r]*(1.f/170.f) - mu*mu;
          const float hn = (acc1[nt][r]-mu)*rsqrtf(var+1e-6f)*g2 + be;
          const float u = kA*(hn + kB*hn*hn*hn);
          const float gl = hn / (1.f + __expf(-2.f*u));
          Abuf[p*ASTR + col] = __float2bfloat16(gl);
        }
      }
    }
  }
  __syncthreads();

  // ---- fc2 GEMM (K=192) + ls2*res -> xt (coalesced) ----
  {
    bf16x8 af[6];
    #pragma unroll
    for(int s = 0; s < 6; s++) af[s] = *(const bf16x8*)&Abuf[l15*ASTR + s*32 + q4*8];
    f32x4 acc[2];
    #pragma unroll
    for(int nt = 0; nt < 2; nt++){ acc[nt][0]=0.f; acc[nt][1]=0.f; acc[nt][2]=0.f; acc[nt][3]=0.f; }
    #pragma unroll
    for(int nt = 0; nt < 2; nt++){
      const int n = (wave*2+nt)*16 + l15;
      #pragma unroll
      for(int s = 0; s < 6; s++){
        bf16x8 bf = *(const bf16x8*)&packF2[((s*128 + n)*4 + q4)*8];
        acc[nt] = __builtin_amdgcn_mfma_f32_16x16x32_bf16(af[s], bf, acc[nt], 0,0,0);
      }
    }
    #pragma unroll
    for(int nt = 0; nt < 2; nt++){
      const int col = (wave*2+nt)*16 + l15;
      const float bf2 = fc2_b[col], l2 = ls2[col];
      #pragma unroll
      for(int r = 0; r < 4; r++){
        const int p = q4*4 + r;
        xt_out[p0 + ((size_t)(p>>2)<<14) + (size_t)((p&3)<<7) + col] =
          xh[nt][r] + l2*(acc[nt][r] + bf2);
      }
    }
  }
}

// ---- K_out: 64x64 tiled transpose xt (B,HW,C) -> out (B,C,H,W) ----
__global__ void __launch_bounds__(256)
k_tout(const float* __restrict__ xt, float* __restrict__ out){
  __shared__ float tile[64][65];
  const int bx = blockIdx.x, tid = threadIdx.x;
  const int b = bx >> 9, r2 = bx & 511;
  const int pb = (r2 & 255) * 64, cb = (r2 >> 8) * 64;
  const int tx = tid & 63, ty = tid >> 6;
  #pragma unroll
  for(int r = 0; r < 64; r += 4)
    tile[ty+r][tx] = xt[(size_t)((b<<14) + pb + ty + r)*128 + cb + tx];
  __syncthreads();
  #pragma unroll
  for(int r = 0; r < 64; r += 4)
    out[(size_t)(b*128 + cb + ty + r)*16384 + pb + tx] = tile[tx][ty+r];
}

extern "C" void kernel_launch(void* const* d_in, const int* in_sizes, int n_in,
                              void* d_out, int out_size, void* d_ws, size_t ws_size,
                              hipStream_t stream){
  const float* x      = (const float*)d_in[0];
  const float* qkv_w  = (const float*)d_in[1];
  const float* qkv_b  = (const float*)d_in[2];
  const float* qg     = (const float*)d_in[3];
  const float* qb     = (const float*)d_in[4];
  const float* kg     = (const float*)d_in[5];
  const float* kb     = (const float*)d_in[6];
  const float* proj_w = (const float*)d_in[7];
  const float* proj_b = (const float*)d_in[8];
  const float* n1g    = (const float*)d_in[9];
  const float* n1b    = (const float*)d_in[10];
  const float* n2g    = (const float*)d_in[11];
  const float* n2b    = (const float*)d_in[12];
  const float* ls1    = (const float*)d_in[13];
  const float* ls2    = (const float*)d_in[14];
  const float* fc1_w  = (const float*)d_in[15];
  const float* fc1_b  = (const float*)d_in[16];
  const float* mg     = (const float*)d_in[17];
  const float* mb     = (const float*)d_in[18];
  const float* fc2_w  = (const float*)d_in[19];
  const float* fc2_b  = (const float*)d_in[20];

  float* ws  = (float*)d_ws;
  float* xt  = ws;
  float* kcb = ws + 4194304;
  float* vcb = ws + 5242880;
  BF* pk     = (BF*)(ws + 6291456);
  BF* packQ  = pk;
  BF* packP  = pk + 49152;
  BF* packF1 = pk + 65536;
  BF* packF2 = pk + 88064;

  k_pre <<<1976, 256, 0, stream>>>(x, qkv_w, proj_w, fc1_w, fc2_w, qkv_b,
                                   kg, kb, n1g, n1b, xt, pk, kcb, vcb);
  k_cell<<<2048, 256, 0, stream>>>(xt, packQ, packP, packF1, packF2,
                                   qkv_b, qg, qb, n1g, n1b, proj_b, ls1, ls2,
                                   n2g, n2b, fc1_b, mg, mb, fc2_b,
                                   kcb, vcb, xt);
  k_tout<<<1024, 256, 0, stream>>>(xt, (float*)d_out);
}

// Round 6
// 234.433 us; speedup vs baseline: 1.0609x; 1.0609x over previous
//
#include <hip/hip_runtime.h>
#include <hip/hip_bf16.h>

typedef __hip_bfloat16 BF;
typedef __attribute__((ext_vector_type(8))) short bf16x8;
typedef __attribute__((ext_vector_type(4))) float f32x4;
typedef __attribute__((ext_vector_type(4))) unsigned short us4;

// B=2, C=128, H=W=128, K=8, STRIDE=2, DIL=2, NH=8, dh=16, HID=170, Hc=Wc=64
// fp32 in / fp32 out. MFMA (bf16, fp32 acc) everywhere.
// ws (floats): xt[0,4194304) kcb[+1048576) vcb[+1048576) ; packs (bf16) at 6291456

#define ASTR 200   // k_cell Abuf row stride (bf16)
#define KSTR 136   // k_pre(kv) Abuf row stride (bf16)

__device__ __forceinline__ short bfr(float f){
  union{float f; unsigned u;} c; c.f = f;
  const unsigned u = c.u + 0x7FFFu + ((c.u >> 16) & 1u);
  return (short)(u >> 16);
}
__device__ __forceinline__ bf16x8 pk8(float4 a, float4 b){
  bf16x8 r;
  r[0]=bfr(a.x); r[1]=bfr(a.y); r[2]=bfr(a.z); r[3]=bfr(a.w);
  r[4]=bfr(b.x); r[5]=bfr(b.y); r[6]=bfr(b.z); r[7]=bfr(b.w);
  return r;
}

// sum-reduce 16 vals across a 128-thr half (2 waves) of a 256-thr block
__device__ __forceinline__ void gsum16h(float v[16], float* red, int tid){
  #pragma unroll
  for(int s = 1; s < 64; s <<= 1){
    #pragma unroll
    for(int i = 0; i < 16; i++) v[i] += __shfl_xor(v[i], s);
  }
  const int wid = tid >> 6, half = tid >> 7;
  __syncthreads();
  if((tid & 63) == 0){
    #pragma unroll
    for(int i = 0; i < 16; i++) red[wid*16 + i] = v[i];
  }
  __syncthreads();
  #pragma unroll
  for(int i = 0; i < 16; i++) v[i] = red[half*32 + i] + red[half*32 + 16 + i];
}

// per-half row-stat reduction (k_pre kv)
__device__ __forceinline__ void rowredh(float s1[4], float s2[4], float* red, int tid){
  const int lane = tid & 63, wid = tid >> 6, half = tid >> 7;
  #pragma unroll
  for(int m = 1; m < 16; m <<= 1){
    #pragma unroll
    for(int r = 0; r < 4; r++){ s1[r] += __shfl_xor(s1[r], m); s2[r] += __shfl_xor(s2[r], m); }
  }
  const int q4 = lane >> 4;
  __syncthreads();
  if((lane & 15) == 0){
    #pragma unroll
    for(int r = 0; r < 4; r++){
      red[wid*32 + q4*4 + r]      = s1[r];
      red[wid*32 + 16 + q4*4 + r] = s2[r];
    }
  }
  __syncthreads();
  #pragma unroll
  for(int r = 0; r < 4; r++){
    s1[r] = red[half*64 + q4*4 + r]      + red[half*64 + 32 + q4*4 + r];
    s2[r] = red[half*64 + 16 + q4*4 + r] + red[half*64 + 48 + q4*4 + r];
  }
}

// 4-wave row-stat reduction (k_cell): rows 0..15 = px, stats over 128 cols
__device__ __forceinline__ void rowred4(float s1[4], float s2[4], float* red,
                                        int wave, int lane){
  #pragma unroll
  for(int m = 1; m < 16; m <<= 1){
    #pragma unroll
    for(int r = 0; r < 4; r++){ s1[r] += __shfl_xor(s1[r], m); s2[r] += __shfl_xor(s2[r], m); }
  }
  const int q4 = lane >> 4;
  __syncthreads();
  if((lane & 15) == 0){
    #pragma unroll
    for(int r = 0; r < 4; r++){
      red[wave*32 + q4*4 + r]      = s1[r];
      red[wave*32 + 16 + q4*4 + r] = s2[r];
    }
  }
  __syncthreads();
  #pragma unroll
  for(int r = 0; r < 4; r++){
    s1[r] = red[q4*4 + r] + red[32 + q4*4 + r] + red[64 + q4*4 + r] + red[96 + q4*4 + r];
    s2[r] = red[16 + q4*4 + r] + red[48 + q4*4 + r] + red[80 + q4*4 + r] + red[112 + q4*4 + r];
  }
}

// ---- K_pre: fused {coarse k,v | weight pack | transpose x->xt} ----
// kv blocks FIRST (longest serial chain starts at t=0); kv reads x and qkv_w
// directly (no dependency on the pack section -> no ordering race).
__global__ void __launch_bounds__(256)
k_pre(const float* __restrict__ x,
      const float* __restrict__ qkv_w, const float* __restrict__ proj_w,
      const float* __restrict__ fc1_w, const float* __restrict__ fc2_w,
      const float* __restrict__ qkv_b,
      const float* __restrict__ kg, const float* __restrict__ kb,
      const float* __restrict__ n1g, const float* __restrict__ n1b,
      float* __restrict__ xt, BF* __restrict__ pk,
      float* __restrict__ kcb, float* __restrict__ vcb){
  __shared__ __align__(16) unsigned char sm[16640];
  const int bx = blockIdx.x, tid = threadIdx.x;

  if(bx >= 952){                       // ---- transpose x (B,C,H,W) -> xt (B,HW,C)
    float (*tile)[65] = (float(*)[65])sm;
    const int bxt = bx - 952;
    const int b = bxt >> 9, r2 = bxt & 511;
    const int pb = (r2 & 255) * 64, cb = (r2 >> 8) * 64;
    const int tx = tid & 63, ty = tid >> 6;
    #pragma unroll
    for(int r = 0; r < 64; r += 4)
      tile[ty+r][tx] = x[(size_t)(b*128 + cb+ty+r)*16384 + pb + tx];
    __syncthreads();
    #pragma unroll
    for(int r = 0; r < 64; r += 4)
      xt[(size_t)((b<<14) + pb + ty + r)*128 + cb + tx] = tile[tx][ty+r];
    return;
  }
  if(bx >= 512){                       // ---- weight pack (consumed by k_cell only)
    const int idx = (bx - 512) * 256 + tid;
    if(idx >= 112640) return;
    float val;
    if(idx < 49152){
      const int reg = idx >> 14, l = idx & 16383;
      const int j = l & 7, q = (l>>3)&3, n = (l>>5)&127, s = l>>12;
      val = qkv_w[(reg*128 + n)*128 + (s*32 + q*8 + j)];
    } else if(idx < 65536){
      const int l = idx - 49152;
      const int j = l&7, q=(l>>3)&3, n=(l>>5)&127, s=l>>12;
      val = proj_w[n*128 + (s*32+q*8+j)];
    } else if(idx < 88064){
      const int l = idx - 65536;
      const int j = l&7, q=(l>>3)&3, rem = l>>5;
      const int n = rem % 176, s = rem / 176;
      const int k = s*32+q*8+j;
      val = (n < 170) ? fc1_w[n*128 + k] : 0.f;
    } else {
      const int l = idx - 88064;
      const int j = l&7, q=(l>>3)&3, n=(l>>5)&127, s=l>>12;
      const int k = s*32+q*8+j;
      val = (k < 170) ? fc2_w[n*170 + k] : 0.f;
    }
    pk[idx] = __float2bfloat16(val);
    return;
  }

  // ---- kv: 16 coarse px/block, two independent 128-thr halves ----
  BF* const Abuf = (BF*)sm;                    // 2 halves x [16][KSTR]
  float* const red = (float*)(sm + 8704);      // 128 floats
  const int lane = tid & 63, half = tid >> 7, wh = (tid >> 6) & 1, c = tid & 127;
  const int l15 = lane & 15, q4 = lane >> 4;
  const int cp0 = bx * 16;
  const int b = cp0 >> 12, ic = (cp0 & 4095) >> 6, jb = cp0 & 63;
  BF* const AbufH = Abuf + half*16*KSTR;

  float xv[8];
  {
    const size_t off = (size_t)(b*128 + c)*16384 + (size_t)(2*ic)*128 + 2*(jb + half*8);
    const float4* xp4 = (const float4*)(x + off);
    const float4 f0 = xp4[0], f1 = xp4[1], f2 = xp4[2], f3 = xp4[3];
    xv[0]=f0.x; xv[1]=f0.z; xv[2]=f1.x; xv[3]=f1.z;
    xv[4]=f2.x; xv[5]=f2.z; xv[6]=f3.x; xv[7]=f3.z;
  }
  float st[16];
  #pragma unroll
  for(int r = 0; r < 8; r++){ st[r] = xv[r]; st[8+r] = xv[r]*xv[r]; }
  gsum16h(st, red, tid);
  {
    const float g = n1g[c], be = n1b[c];
    #pragma unroll
    for(int r = 0; r < 8; r++){
      const float mu = st[r]*(1.f/128.f);
      const float var = st[8+r]*(1.f/128.f) - mu*mu;
      AbufH[r*KSTR + c] = __float2bfloat16((xv[r]-mu)*rsqrtf(var+1e-6f)*g + be);
    }
  }
  __syncthreads();
  bf16x8 af[4];
  #pragma unroll
  for(int s = 0; s < 4; s++) af[s] = *(const bf16x8*)&AbufH[l15*KSTR + s*32 + q4*8];

  // ---- k GEMM (B-fragments straight from qkv_w, bf16-packed inline) ----
  f32x4 acc[4];
  #pragma unroll
  for(int nt = 0; nt < 4; nt++){ acc[nt][0]=0.f; acc[nt][1]=0.f; acc[nt][2]=0.f; acc[nt][3]=0.f; }
  #pragma unroll
  for(int nt = 0; nt < 4; nt++){
    const int n = (wh*4+nt)*16 + l15;
    #pragma unroll
    for(int s = 0; s < 4; s++){
      const float* wp = qkv_w + (size_t)(128 + n)*128 + s*32 + q4*8;
      acc[nt] = __builtin_amdgcn_mfma_f32_16x16x32_bf16(
        af[s], pk8(*(const float4*)wp, *(const float4*)(wp+4)), acc[nt], 0,0,0);
    }
  }
  float s1[4], s2[4];
  #pragma unroll
  for(int r = 0; r < 4; r++){ s1[r]=0.f; s2[r]=0.f; }
  #pragma unroll
  for(int nt = 0; nt < 4; nt++){
    const float colb = qkv_b[128 + (wh*4+nt)*16 + l15];
    #pragma unroll
    for(int r = 0; r < 4; r++){
      const float vv = acc[nt][r] + colb;
      acc[nt][r] = vv; s1[r] += vv; s2[r] += vv*vv;
    }
  }
  rowredh(s1, s2, red, tid);
  #pragma unroll
  for(int nt = 0; nt < 4; nt++){
    const int col = (wh*4+nt)*16 + l15;
    const float g = kg[col], be = kb[col];
    #pragma unroll
    for(int r = 0; r < 4; r++){
      const int row = q4*4 + r;
      if(row < 8){
        const float mu = s1[r]*(1.f/128.f);
        const float var = s2[r]*(1.f/128.f) - mu*mu;
        kcb[(size_t)(cp0 + half*8 + row)*128 + col] = (acc[nt][r]-mu)*rsqrtf(var+1e-6f)*g + be;
      }
    }
  }
  // ---- v GEMM ----
  #pragma unroll
  for(int nt = 0; nt < 4; nt++){ acc[nt][0]=0.f; acc[nt][1]=0.f; acc[nt][2]=0.f; acc[nt][3]=0.f; }
  #pragma unroll
  for(int nt = 0; nt < 4; nt++){
    const int n = (wh*4+nt)*16 + l15;
    #pragma unroll
    for(int s = 0; s < 4; s++){
      const float* wp = qkv_w + (size_t)(256 + n)*128 + s*32 + q4*8;
      acc[nt] = __builtin_amdgcn_mfma_f32_16x16x32_bf16(
        af[s], pk8(*(const float4*)wp, *(const float4*)(wp+4)), acc[nt], 0,0,0);
    }
  }
  #pragma unroll
  for(int nt = 0; nt < 4; nt++){
    const int col = (wh*4+nt)*16 + l15;
    const float bv = qkv_b[256 + col];
    #pragma unroll
    for(int r = 0; r < 4; r++){
      const int row = q4*4 + r;
      if(row < 8) vcb[(size_t)(cp0 + half*8 + row)*128 + col] = acc[nt][r] + bv;
    }
  }
}

// ---- K_cell: 256 thr / 16 px (4 cells, 4x4 spatial tile) / all-MFMA ----
// px p: h = 4ip + (p>>2), w = 4jq + (p&3); cell(p) = 2*(p>>3) + ((p>>1)&1);
// lp(p) = 2*((p>>2)&1) + (p&1). Wave w owns cell w for attention.
// Output written DIRECTLY in (B,C,H,W): each thread's 4 fc2 values form one
// aligned float4 (col, h=4ip+q4, w=4jq..4jq+3); XCD swizzle keeps the 4
// consecutive-jq blocks sharing each 64B line on one XCD -> L2 write-merge.
__global__ void __launch_bounds__(256, 5)
k_cell(const float* __restrict__ xt_in,
       const BF* __restrict__ packQ, const BF* __restrict__ packP,
       const BF* __restrict__ packF1, const BF* __restrict__ packF2,
       const float* __restrict__ qkv_b,
       const float* __restrict__ qg, const float* __restrict__ qb,
       const float* __restrict__ n1g, const float* __restrict__ n1b,
       const float* __restrict__ proj_b,
       const float* __restrict__ ls1, const float* __restrict__ ls2,
       const float* __restrict__ n2g, const float* __restrict__ n2b,
       const float* __restrict__ fc1_b,
       const float* __restrict__ mg, const float* __restrict__ mb,
       const float* __restrict__ fc2_b,
       const float* __restrict__ kcb, const float* __restrict__ vcb,
       float* __restrict__ out){
  __shared__ __align__(16) BF uni[9216];
  BF* const Abuf = uni;                        // [16][ASTR]
  __shared__ float xvL[2048];                  // [16px][128ch]
  __shared__ __align__(16) ushort qnH[2176];   // [4cell][136pad][4lp]
  __shared__ ushort cidx2[256];                // [4cell][64] safe coarse idx
  float* const red = (float*)qnH;              // 128 floats, disjoint live range
  const int tid = threadIdx.x, wave = tid>>6, lane = tid&63;
  const int l15 = lane & 15, q4 = lane >> 4;

  // XCD-aware swizzle (bijective: 2048 % 8 == 0, chunks of 256 per XCD)
  const int bx0 = blockIdx.x;
  const int bx = ((bx0 & 7) << 8) | (bx0 >> 3);
  const int b = bx >> 10, rem = bx & 1023, ip = rem >> 5, jq = rem & 31;
  const size_t p0 = (size_t)b*2097152 + (size_t)(512*ip + 4*jq)*128;
  const int c = tid & 127, half = tid >> 7;

  float xv[8];
  #pragma unroll
  for(int r = 0; r < 8; r++){
    const int p = half*8 + r;
    const size_t pr = p0 + ((size_t)(p>>2)<<14) + (size_t)((p&3)<<7);
    xv[r] = xt_in[pr + c];
    xvL[p*128 + c] = xv[r];
  }
  {                                            // neighbor indices, 4 cells
    const int cell = tid >> 6, e = tid & 63;
    const int i = e >> 3, j = e & 7;
    const int ic = 2*ip + (cell>>1), jcc = 2*jq + (cell&1);
    const int ri = ic + 2*i - 8, rj = jcc + 2*j - 8;
    const bool ok = (rj >= 0) && (rj < 64) && (ri >= 0) && (ri < 64);
    cidx2[cell*64 + e] = ok ? (ushort)(b*4096 + ri*64 + rj) : (ushort)0;
  }

  // ---- LN1 ----
  float st[16];
  #pragma unroll
  for(int r = 0; r < 8; r++){ st[r] = xv[r]; st[8+r] = xv[r]*xv[r]; }
  gsum16h(st, red, tid);
  {
    const float g = n1g[c], be = n1b[c];
    #pragma unroll
    for(int r = 0; r < 8; r++){
      const int p = half*8 + r;
      const float mu = st[r]*(1.f/128.f);
      const float var = st[8+r]*(1.f/128.f) - mu*mu;
      Abuf[p*ASTR + c] = __float2bfloat16((xv[r]-mu)*rsqrtf(var+1e-6f)*g + be);
    }
  }
  __syncthreads();

  // ---- q GEMM (M=16) + q-LN -> qnH ----
  {
    bf16x8 af[4];
    #pragma unroll
    for(int s = 0; s < 4; s++) af[s] = *(const bf16x8*)&Abuf[l15*ASTR + s*32 + q4*8];
    f32x4 acc[2];
    #pragma unroll
    for(int nt = 0; nt < 2; nt++){ acc[nt][0]=0.f; acc[nt][1]=0.f; acc[nt][2]=0.f; acc[nt][3]=0.f; }
    #pragma unroll
    for(int nt = 0; nt < 2; nt++){
      const int n = (wave*2+nt)*16 + l15;
      #pragma unroll
      for(int s = 0; s < 4; s++){
        bf16x8 bf = *(const bf16x8*)&packQ[((s*128 + n)*4 + q4)*8];
        acc[nt] = __builtin_amdgcn_mfma_f32_16x16x32_bf16(af[s], bf, acc[nt], 0,0,0);
      }
    }
    float s1[4], s2[4];
    #pragma unroll
    for(int r = 0; r < 4; r++){ s1[r]=0.f; s2[r]=0.f; }
    #pragma unroll
    for(int nt = 0; nt < 2; nt++){
      const float cb2 = qkv_b[(wave*2+nt)*16 + l15];
      #pragma unroll
      for(int r = 0; r < 4; r++){
        const float vv = acc[nt][r] + cb2;
        acc[nt][r] = vv; s1[r] += vv; s2[r] += vv*vv;
      }
    }
    rowred4(s1, s2, red, wave, lane);
    short tw[2][4];
    {
      float mu[4], rs[4];
      #pragma unroll
      for(int r = 0; r < 4; r++){
        mu[r] = s1[r]*(1.f/128.f);
        rs[r] = rsqrtf(s2[r]*(1.f/128.f) - mu[r]*mu[r] + 1e-6f);
      }
      #pragma unroll
      for(int nt = 0; nt < 2; nt++){
        const int col = (wave*2+nt)*16 + l15;
        const float g = qg[col], be = qb[col];
        #pragma unroll
        for(int r = 0; r < 4; r++)
          tw[nt][r] = bfr((acc[nt][r]-mu[r])*rs[r]*g + be);
      }
    }
    __syncthreads();            // red (aliased with qnH) fully consumed
    #pragma unroll
    for(int nt = 0; nt < 2; nt++){
      const int col = (wave*2+nt)*16 + l15;
      const int colp = col + (col >> 4);
      #pragma unroll
      for(int r = 0; r < 4; r++){
        const int cell = 2*(q4>>1) + ((r>>1)&1);
        const int lp   = 2*(q4&1) + (r&1);
        qnH[cell*544 + colp*4 + lp] = (ushort)tw[nt][r];
      }
    }
  }
  __syncthreads();

  // ---- attention: wave w owns cell w, 2 head-groups, no inner barriers ----
  const int hsub = l15 >> 2, px = l15 & 3;
  const int par = q4 >> 1, dbase = (q4 & 1) * 8;
  BF* const attw = uni + wave*2304;
  ushort* const Vt = (ushort*)attw;            // [16][72]
  ushort* const Pb = (ushort*)(attw + 1152);   // [16][72]
  const ushort* cidx = cidx2 + wave*64;
  const ushort* qp = qnH + wave*544;
  const int ic = 2*ip + (wave>>1), jcc = 2*jq + (wave&1);
  const int i0 = l15 >> 3;
  const int rj = jcc + 2*(l15 & 7) - 8;
  const bool vj = (rj >= 0) && (rj < 64);
  float madd[4];
  #pragma unroll
  for(int nt = 0; nt < 4; nt++){
    const int ri = ic + 2*(nt*2 + i0) - 8;
    madd[nt] = (vj && ri >= 0 && ri < 64) ? 0.f : -1e30f;
  }

  f32x4 oC[2];
  #pragma unroll
  for(int hg = 0; hg < 2; hg++){
    // block-diagonal q A-fragments
    bf16x8 afq0, afq1;
    {
      const int idx0 = (hg*64 + hsub*16 + dbase + (hg*4 + hsub))*4 + px;
      short bq[8];
      #pragma unroll
      for(int j = 0; j < 8; j++) bq[j] = (short)qp[idx0 + 4*j];
      const bool a0 = (par == hsub), a1 = ((2 + par) == hsub);
      #pragma unroll
      for(int j = 0; j < 8; j++){
        afq0[j] = a0 ? bq[j] : (short)0;
        afq1[j] = a1 ? bq[j] : (short)0;
      }
    }
    // QK: 8 MFMA
    f32x4 accq[4];
    #pragma unroll
    for(int nt = 0; nt < 4; nt++){ accq[nt][0]=0.f; accq[nt][1]=0.f; accq[nt][2]=0.f; accq[nt][3]=0.f; }
    #pragma unroll
    for(int nt = 0; nt < 4; nt++){
      const float* kp = kcb + ((size_t)cidx[nt*16 + l15] << 7) + hg*64 + q4*8;
      const float4 k00 = *(const float4*)kp;
      const float4 k01 = *(const float4*)(kp + 4);
      const float4 k10 = *(const float4*)(kp + 32);
      const float4 k11 = *(const float4*)(kp + 36);
      accq[nt] = __builtin_amdgcn_mfma_f32_16x16x32_bf16(afq0, pk8(k00,k01), accq[nt], 0,0,0);
      accq[nt] = __builtin_amdgcn_mfma_f32_16x16x32_bf16(afq1, pk8(k10,k11), accq[nt], 0,0,0);
    }
    // softmax in-register; unnormalized e (bf16) -> Pb
    float inv[4];
    #pragma unroll
    for(int reg = 0; reg < 4; reg++){
      const float s0 = accq[0][reg]*0.25f + madd[0];
      const float s1 = accq[1][reg]*0.25f + madd[1];
      const float s2 = accq[2][reg]*0.25f + madd[2];
      const float s3 = accq[3][reg]*0.25f + madd[3];
      float m = fmaxf(fmaxf(s0,s1), fmaxf(s2,s3));
      #pragma unroll
      for(int sft = 1; sft < 16; sft <<= 1) m = fmaxf(m, __shfl_xor(m, sft));
      const float e0 = __expf(s0-m), e1 = __expf(s1-m);
      const float e2 = __expf(s2-m), e3 = __expf(s3-m);
      ushort* pr = Pb + (q4*4 + reg)*72 + l15;
      pr[0]  = (ushort)bfr(e0);
      pr[16] = (ushort)bfr(e1);
      pr[32] = (ushort)bfr(e2);
      pr[48] = (ushort)bfr(e3);
      float es = e0+e1+e2+e3;
      #pragma unroll
      for(int sft = 1; sft < 16; sft <<= 1) es += __shfl_xor(es, sft);
      inv[reg] = 1.f/es;
    }
    const bf16x8 pa0 = *(const bf16x8*)(Pb + l15*72 + q4*8);
    const bf16x8 pa1 = *(const bf16x8*)(Pb + l15*72 + 32 + q4*8);

    // PV: per head stage V, 2 MFMA; keep own head's rows
    f32x4 oSel; oSel[0]=0.f; oSel[1]=0.f; oSel[2]=0.f; oSel[3]=0.f;
    #pragma unroll
    for(int hs = 0; hs < 4; hs++){
      const int h = hg*4 + hs;
      float4 vv[4];
      #pragma unroll
      for(int it = 0; it < 4; it++)
        vv[it] = *(const float4*)(vcb + ((size_t)cidx[l15*4 + it] << 7) + h*16 + q4*4);
      #pragma unroll
      for(int dd = 0; dd < 4; dd++){
        us4 w;
        w[0] = (unsigned short)bfr(((const float*)&vv[0])[dd]);
        w[1] = (unsigned short)bfr(((const float*)&vv[1])[dd]);
        w[2] = (unsigned short)bfr(((const float*)&vv[2])[dd]);
        w[3] = (unsigned short)bfr(((const float*)&vv[3])[dd]);
        *(us4*)(Vt + (q4*4 + dd)*72 + l15*4) = w;
      }
      const bf16x8 bv0 = *(const bf16x8*)(Vt + l15*72 + q4*8);
      const bf16x8 bv1 = *(const bf16x8*)(Vt + l15*72 + 32 + q4*8);
      f32x4 accv; accv[0]=0.f; accv[1]=0.f; accv[2]=0.f; accv[3]=0.f;
      accv = __builtin_amdgcn_mfma_f32_16x16x32_bf16(pa0, bv0, accv, 0,0,0);
      accv = __builtin_amdgcn_mfma_f32_16x16x32_bf16(pa1, bv1, accv, 0,0,0);
      if(q4 == hs){ oSel[0]=accv[0]; oSel[1]=accv[1]; oSel[2]=accv[2]; oSel[3]=accv[3]; }
    }
    oC[hg][0] = oSel[0]*inv[0]; oC[hg][1] = oSel[1]*inv[1];
    oC[hg][2] = oSel[2]*inv[2]; oC[hg][3] = oSel[3]*inv[3];
  }
  __syncthreads();
  // ao -> Abuf[px p][head*16 + d]
  {
    ushort* ab = (ushort*)Abuf;
    #pragma unroll
    for(int hg = 0; hg < 2; hg++){
      const int col = (hg*4 + q4)*16 + l15;
      #pragma unroll
      for(int reg = 0; reg < 4; reg++){
        const int row_p = 8*(wave>>1) + 4*(reg>>1) + 2*(wave&1) + (reg&1);
        ab[row_p*ASTR + col] = (ushort)bfr(oC[hg][reg]);
      }
    }
  }
  __syncthreads();

  // ---- proj GEMM + ls1*res -> xh, LN2 -> Abuf ----
  float xh[2][4];
  {
    bf16x8 af[4];
    #pragma unroll
    for(int s = 0; s < 4; s++) af[s] = *(const bf16x8*)&Abuf[l15*ASTR + s*32 + q4*8];
    f32x4 acc[2];
    #pragma unroll
    for(int nt = 0; nt < 2; nt++){ acc[nt][0]=0.f; acc[nt][1]=0.f; acc[nt][2]=0.f; acc[nt][3]=0.f; }
    #pragma unroll
    for(int nt = 0; nt < 2; nt++){
      const int n = (wave*2+nt)*16 + l15;
      #pragma unroll
      for(int s = 0; s < 4; s++){
        bf16x8 bf = *(const bf16x8*)&packP[((s*128 + n)*4 + q4)*8];
        acc[nt] = __builtin_amdgcn_mfma_f32_16x16x32_bf16(af[s], bf, acc[nt], 0,0,0);
      }
    }
    float s1[4], s2[4];
    #pragma unroll
    for(int r = 0; r < 4; r++){ s1[r]=0.f; s2[r]=0.f; }
    #pragma unroll
    for(int nt = 0; nt < 2; nt++){
      const int col = (wave*2+nt)*16 + l15;
      const float bp = proj_b[col], l1 = ls1[col];
      #pragma unroll
      for(int r = 0; r < 4; r++){
        const int p = q4*4 + r;
        const float hx = xvL[p*128 + col] + l1*(acc[nt][r] + bp);
        xh[nt][r] = hx; s1[r] += hx; s2[r] += hx*hx;
      }
    }
    rowred4(s1, s2, red, wave, lane);
    #pragma unroll
    for(int nt = 0; nt < 2; nt++){
      const int col = (wave*2+nt)*16 + l15;
      const float g2 = n2g[col], be = n2b[col];
      #pragma unroll
      for(int r = 0; r < 4; r++){
        const int p = q4*4 + r;
        const float mu = s1[r]*(1.f/128.f);
        const float var = s2[r]*(1.f/128.f) - mu*mu;
        Abuf[p*ASTR + col] =
          __float2bfloat16((xh[nt][r]-mu)*rsqrtf(var+1e-6f)*g2 + be);
      }
    }
  }
  __syncthreads();

  // ---- fc1 GEMM (N=176, tiles 3/3/3/2) + midLN + gelu -> Abuf ----
  {
    bf16x8 af[4];
    #pragma unroll
    for(int s = 0; s < 4; s++) af[s] = *(const bf16x8*)&Abuf[l15*ASTR + s*32 + q4*8];
    const int NT1 = (wave < 3) ? 3 : 2;
    const int tb  = (wave < 3) ? wave*3 : 9;
    f32x4 acc1[3];
    #pragma unroll
    for(int nt = 0; nt < 3; nt++){ acc1[nt][0]=0.f; acc1[nt][1]=0.f; acc1[nt][2]=0.f; acc1[nt][3]=0.f; }
    for(int nt = 0; nt < NT1; nt++){
      const int n = (tb + nt)*16 + l15;
      #pragma unroll
      for(int s = 0; s < 4; s++){
        bf16x8 bf = *(const bf16x8*)&packF1[((s*176 + n)*4 + q4)*8];
        acc1[nt] = __builtin_amdgcn_mfma_f32_16x16x32_bf16(af[s], bf, acc1[nt], 0,0,0);
      }
    }
    float s1[4], s2[4];
    #pragma unroll
    for(int r = 0; r < 4; r++){ s1[r]=0.f; s2[r]=0.f; }
    for(int nt = 0; nt < NT1; nt++){
      const int col = (tb + nt)*16 + l15;
      const float b1 = (col < 170) ? fc1_b[col] : 0.f;
      #pragma unroll
      for(int r = 0; r < 4; r++){
        const float vv = acc1[nt][r] + b1;
        acc1[nt][r] = vv; s1[r] += vv; s2[r] += vv*vv;
      }
    }
    rowred4(s1, s2, red, wave, lane);
    for(int z = tid; z < 352; z += 256){          // zero fc2 K-pad cols 170..191
      const int row = z / 22, colz = 170 + (z - (z/22)*22);
      Abuf[row*ASTR + colz] = __float2bfloat16(0.f);
    }
    const float kA = 0.7978845608028654f, kB = 0.044715f;
    for(int nt = 0; nt < NT1; nt++){
      const int col = (tb + nt)*16 + l15;
      if(col < 170){
        const float g2 = mg[col], be = mb[col];
        #pragma unroll
        for(int r = 0; r < 4; r++){
          const int p = q4*4 + r;
          const float mu = s1[r]*(1.f/170.f);
          const float var = s2[r]*(1.f/170.f) - mu*mu;
          const float hn = (acc1[nt][r]-mu)*rsqrtf(var+1e-6f)*g2 + be;
          const float u = kA*(hn + kB*hn*hn*hn);
          const float gl = hn / (1.f + __expf(-2.f*u));
          Abuf[p*ASTR + col] = __float2bfloat16(gl);
        }
      }
    }
  }
  __syncthreads();

  // ---- fc2 GEMM (K=192) + ls2*res -> out (B,C,H,W) directly ----
  // thread's 4 r-values = (col, h=4ip+q4, w=4jq..4jq+3): one aligned float4.
  {
    bf16x8 af[6];
    #pragma unroll
    for(int s = 0; s < 6; s++) af[s] = *(const bf16x8*)&Abuf[l15*ASTR + s*32 + q4*8];
    f32x4 acc[2];
    #pragma unroll
    for(int nt = 0; nt < 2; nt++){ acc[nt][0]=0.f; acc[nt][1]=0.f; acc[nt][2]=0.f; acc[nt][3]=0.f; }
    #pragma unroll
    for(int nt = 0; nt < 2; nt++){
      const int n = (wave*2+nt)*16 + l15;
      #pragma unroll
      for(int s = 0; s < 6; s++){
        bf16x8 bf = *(const bf16x8*)&packF2[((s*128 + n)*4 + q4)*8];
        acc[nt] = __builtin_amdgcn_mfma_f32_16x16x32_bf16(af[s], bf, acc[nt], 0,0,0);
      }
    }
    #pragma unroll
    for(int nt = 0; nt < 2; nt++){
      const int col = (wave*2+nt)*16 + l15;
      const float bf2 = fc2_b[col], l2 = ls2[col];
      float4 o4;
      o4.x = xh[nt][0] + l2*(acc[nt][0] + bf2);
      o4.y = xh[nt][1] + l2*(acc[nt][1] + bf2);
      o4.z = xh[nt][2] + l2*(acc[nt][2] + bf2);
      o4.w = xh[nt][3] + l2*(acc[nt][3] + bf2);
      *(float4*)(out + (size_t)(b*128 + col)*16384 + (size_t)(4*ip + q4)*128 + 4*jq) = o4;
    }
  }
}

extern "C" void kernel_launch(void* const* d_in, const int* in_sizes, int n_in,
                              void* d_out, int out_size, void* d_ws, size_t ws_size,
                              hipStream_t stream){
  const float* x      = (const float*)d_in[0];
  const float* qkv_w  = (const float*)d_in[1];
  const float* qkv_b  = (const float*)d_in[2];
  const float* qg     = (const float*)d_in[3];
  const float* qb     = (const float*)d_in[4];
  const float* kg     = (const float*)d_in[5];
  const float* kb     = (const float*)d_in[6];
  const float* proj_w = (const float*)d_in[7];
  const float* proj_b = (const float*)d_in[8];
  const float* n1g    = (const float*)d_in[9];
  const float* n1b    = (const float*)d_in[10];
  const float* n2g    = (const float*)d_in[11];
  const float* n2b    = (const float*)d_in[12];
  const float* ls1    = (const float*)d_in[13];
  const float* ls2    = (const float*)d_in[14];
  const float* fc1_w  = (const float*)d_in[15];
  const float* fc1_b  = (const float*)d_in[16];
  const float* mg     = (const float*)d_in[17];
  const float* mb     = (const float*)d_in[18];
  const float* fc2_w  = (const float*)d_in[19];
  const float* fc2_b  = (const float*)d_in[20];

  float* ws  = (float*)d_ws;
  float* xt  = ws;
  float* kcb = ws + 4194304;
  float* vcb = ws + 5242880;
  BF* pk     = (BF*)(ws + 6291456);
  BF* packQ  = pk;
  BF* packP  = pk + 49152;
  BF* packF1 = pk + 65536;
  BF* packF2 = pk + 88064;

  k_pre <<<1976, 256, 0, stream>>>(x, qkv_w, proj_w, fc1_w, fc2_w, qkv_b,
                                   kg, kb, n1g, n1b, xt, pk, kcb, vcb);
  k_cell<<<2048, 256, 0, stream>>>(xt, packQ, packP, packF1, packF2,
                                   qkv_b, qg, qb, n1g, n1b, proj_b, ls1, ls2,
                                   n2g, n2b, fc1_b, mg, mb, fc2_b,
                                   kcb, vcb, (float*)d_out);
}